// Round 2
// baseline (624.983 us; speedup 1.0000x reference)
//
#include <hip/hip_runtime.h>
#include <hip/hip_bf16.h>

using bf16 = __hip_bfloat16;
typedef __attribute__((ext_vector_type(4))) float f32x4;
typedef __attribute__((ext_vector_type(8))) short bf16x8;   // 8 bf16 = 4 VGPRs (MFMA A/B frag)

constexpr int Ntok   = 4096;
constexpr int Cdim   = 768;
constexpr int Hn     = 6;
constexpr int HD     = 128;
constexpr int QKcols = 1536;   // 2*Cdim

// ---------------------------------------------------------------------------
// Transpose + cast: W[K][N] fp32 -> Wt[N][K] bf16  (tiny weight matrices)
// ---------------------------------------------------------------------------
__global__ void transpose_kernel(const float* __restrict__ W, bf16* __restrict__ Wt,
                                 int K, int N) {
    __shared__ bf16 tile[32][33];
    const int n0 = blockIdx.x * 32, k0 = blockIdx.y * 32;
    const int tx = threadIdx.x, ty = threadIdx.y;      // blockDim (32,8)
    for (int i = 0; i < 32; i += 8)
        tile[ty + i][tx] = __float2bfloat16(W[(size_t)(k0 + ty + i) * N + n0 + tx]);
    __syncthreads();
    for (int i = 0; i < 32; i += 8)
        Wt[(size_t)(n0 + ty + i) * K + k0 + tx] = tile[tx][ty + i];
}

__device__ inline int4 cvt8_f32_to_bf16(const float* p) {
    const float4 a0 = *reinterpret_cast<const float4*>(p);
    const float4 a1 = *reinterpret_cast<const float4*>(p + 4);
    union { int4 i; bf16 h[8]; } u;
    u.h[0] = __float2bfloat16(a0.x); u.h[1] = __float2bfloat16(a0.y);
    u.h[2] = __float2bfloat16(a0.z); u.h[3] = __float2bfloat16(a0.w);
    u.h[4] = __float2bfloat16(a1.x); u.h[5] = __float2bfloat16(a1.y);
    u.h[6] = __float2bfloat16(a1.z); u.h[7] = __float2bfloat16(a1.w);
    return u.i;
}

// ---------------------------------------------------------------------------
// GEMM: C[M][N] = A[M][K] @ Bt[N][K]^T (+bias). A fp32 or bf16; C fp32 or bf16.
// 128x128 block tile, BK=32, 4 waves in 2x2, each wave 4x4 tiles of 16x16x32.
// ---------------------------------------------------------------------------
template <bool A_F32, bool C_F32, bool BIAS>
__global__ __launch_bounds__(256) void gemm_bt(const void* __restrict__ Av,
                                               const bf16* __restrict__ Bt,
                                               const float* __restrict__ bias,
                                               void* __restrict__ Cv,
                                               int M, int N, int K) {
    constexpr int BK  = 32;
    constexpr int LDT = BK + 8;                 // row stride 80B -> 2-way bank aliasing (free)
    __shared__ bf16 As[128 * LDT];
    __shared__ bf16 Bs[128 * LDT];

    const int m0   = blockIdx.y * 128, n0 = blockIdx.x * 128;
    const int tid  = threadIdx.x;
    const int wave = tid >> 6, lane = tid & 63;
    const int wq   = wave >> 1, wr = wave & 1;
    const int lm   = lane & 15, quad = lane >> 4;

    f32x4 acc[4][4] = {};

    for (int k0 = 0; k0 < K; k0 += BK) {
        __syncthreads();
#pragma unroll
        for (int r = 0; r < 2; r++) {
            const int chunk = tid + 256 * r;          // 0..511
            const int row = chunk >> 2, kg = (chunk & 3) * 8;
            if constexpr (A_F32) {
                const float* ap = (const float*)Av + (size_t)(m0 + row) * K + k0 + kg;
                *reinterpret_cast<int4*>(&As[row * LDT + kg]) = cvt8_f32_to_bf16(ap);
            } else {
                *reinterpret_cast<int4*>(&As[row * LDT + kg]) =
                    *reinterpret_cast<const int4*>((const bf16*)Av + (size_t)(m0 + row) * K + k0 + kg);
            }
            *reinterpret_cast<int4*>(&Bs[row * LDT + kg]) =
                *reinterpret_cast<const int4*>(Bt + (size_t)(n0 + row) * K + k0 + kg);
        }
        __syncthreads();

        bf16x8 af[4], bfr[4];
#pragma unroll
        for (int t = 0; t < 4; t++) {
            af[t]  = *reinterpret_cast<const bf16x8*>(&As[(wq * 64 + t * 16 + lm) * LDT + quad * 8]);
            bfr[t] = *reinterpret_cast<const bf16x8*>(&Bs[(wr * 64 + t * 16 + lm) * LDT + quad * 8]);
        }
#pragma unroll
        for (int mt = 0; mt < 4; mt++)
#pragma unroll
            for (int nt = 0; nt < 4; nt++)
                acc[mt][nt] = __builtin_amdgcn_mfma_f32_16x16x32_bf16(af[mt], bfr[nt], acc[mt][nt], 0, 0, 0);
    }

    const int cm = m0 + wq * 64, cn = n0 + wr * 64;
#pragma unroll
    for (int mt = 0; mt < 4; mt++) {
#pragma unroll
        for (int nt = 0; nt < 4; nt++) {
            const int col = cn + nt * 16 + lm;
            const float bv = BIAS ? bias[col] : 0.0f;
#pragma unroll
            for (int r = 0; r < 4; r++) {
                const int row = cm + mt * 16 + quad * 4 + r;
                if constexpr (C_F32)
                    ((float*)Cv)[(size_t)row * N + col] = acc[mt][nt][r] + bv;
                else
                    ((bf16*)Cv)[(size_t)row * N + col] = __float2bfloat16(acc[mt][nt][r] + bv);
            }
        }
    }
}

// ---------------------------------------------------------------------------
// Column sum-of-squares over tokens: invn[b][j] = 1/max(||qkv[b,:,j]||, eps)
// ---------------------------------------------------------------------------
__global__ __launch_bounds__(512) void colnorm_kernel(const bf16* __restrict__ qkv,
                                                      float* __restrict__ invn) {
    const int b = blockIdx.y, j0 = blockIdx.x * 64;
    const int jo = threadIdx.x & 63, rg = threadIdx.x >> 6;   // 8 row groups
    const bf16* p = qkv + (size_t)b * Ntok * QKcols + (size_t)rg * 512 * QKcols + j0 + jo;
    float s = 0.0f;
    for (int r = 0; r < 512; r++) {
        const float v = (float)p[(size_t)r * QKcols];
        s += v * v;
    }
    __shared__ float red[512];
    red[threadIdx.x] = s;
    __syncthreads();
    if (threadIdx.x < 64) {
        float t = 0.0f;
#pragma unroll
        for (int g = 0; g < 8; g++) t += red[threadIdx.x + 64 * g];
        invn[b * QKcols + j0 + threadIdx.x] = 1.0f / fmaxf(sqrtf(t), 1e-12f);
    }
}

// ---------------------------------------------------------------------------
// Per-(b,h) Gram over tokens + scale + softmax -> attn weights (bf16 [bh][c][d])
// ---------------------------------------------------------------------------
__global__ __launch_bounds__(256) void gram_softmax_kernel(const bf16* __restrict__ qkv,
                                                           const float* __restrict__ invn,
                                                           const float* __restrict__ temp,
                                                           bf16* __restrict__ attn) {
    constexpr int BKn = 64;
    constexpr int LDT = BKn + 8;                // 72: row stride 144B -> 2-way aliasing
    __shared__ bf16 Qt[HD * LDT];               // [channel][n_local]
    __shared__ bf16 Kt[HD * LDT];

    const int bh = blockIdx.x, b = bh / Hn, h = bh % Hn;
    const int tid = threadIdx.x, wave = tid >> 6, lane = tid & 63;
    const int lm = lane & 15, quad = lane >> 4;
    const size_t base = (size_t)b * Ntok * QKcols;
    const int qoff = h * HD, koff = Cdim + h * HD;

    f32x4 acc[2][8] = {};

    for (int n0 = 0; n0 < Ntok; n0 += BKn) {
        __syncthreads();
#pragma unroll
        for (int r = 0; r < 4; r++) {
            const int chunk = tid + 256 * r;     // 0..1023
            const int nl = chunk & 63;
            const int j0 = (chunk >> 6) * 8;     // 0..120
            bf16 vq[8], vk[8];
            *reinterpret_cast<int4*>(vq) = *reinterpret_cast<const int4*>(qkv + base + (size_t)(n0 + nl) * QKcols + qoff + j0);
            *reinterpret_cast<int4*>(vk) = *reinterpret_cast<const int4*>(qkv + base + (size_t)(n0 + nl) * QKcols + koff + j0);
#pragma unroll
            for (int t = 0; t < 8; t++) {
                Qt[(j0 + t) * LDT + nl] = vq[t];
                Kt[(j0 + t) * LDT + nl] = vk[t];
            }
        }
        __syncthreads();
#pragma unroll
        for (int ks = 0; ks < 2; ks++) {
            bf16x8 aq[2], bk[8];
#pragma unroll
            for (int mt = 0; mt < 2; mt++)
                aq[mt] = *reinterpret_cast<const bf16x8*>(&Qt[(wave * 32 + mt * 16 + lm) * LDT + ks * 32 + quad * 8]);
#pragma unroll
            for (int dt = 0; dt < 8; dt++)
                bk[dt] = *reinterpret_cast<const bf16x8*>(&Kt[(dt * 16 + lm) * LDT + ks * 32 + quad * 8]);
#pragma unroll
            for (int mt = 0; mt < 2; mt++)
#pragma unroll
                for (int dt = 0; dt < 8; dt++)
                    acc[mt][dt] = __builtin_amdgcn_mfma_f32_16x16x32_bf16(aq[mt], bk[dt], acc[mt][dt], 0, 0, 0);
        }
    }

    const float th = temp[h];
    const float* invq = invn + b * QKcols + qoff;
    const float* invk = invn + b * QKcols + koff;
    float ik[8];
#pragma unroll
    for (int dt = 0; dt < 8; dt++) ik[dt] = invk[dt * 16 + lm];

#pragma unroll
    for (int mt = 0; mt < 2; mt++) {
#pragma unroll
        for (int r = 0; r < 4; r++) {
            const int c = wave * 32 + mt * 16 + quad * 4 + r;
            const float iq = invq[c] * th;
            float v[8], mx = -1e30f;
#pragma unroll
            for (int dt = 0; dt < 8; dt++) {
                v[dt] = acc[mt][dt][r] * iq * ik[dt];
                mx = fmaxf(mx, v[dt]);
            }
#pragma unroll
            for (int m = 1; m < 16; m <<= 1) mx = fmaxf(mx, __shfl_xor(mx, m, 16));
            float sum = 0.0f;
#pragma unroll
            for (int dt = 0; dt < 8; dt++) {
                v[dt] = __expf(v[dt] - mx);
                sum += v[dt];
            }
#pragma unroll
            for (int m = 1; m < 16; m <<= 1) sum += __shfl_xor(sum, m, 16);
            const float inv = 1.0f / sum;
            bf16* orow = attn + ((size_t)bh * HD + c) * HD;
#pragma unroll
            for (int dt = 0; dt < 8; dt++)
                orow[dt * 16 + lm] = __float2bfloat16(v[dt] * inv);
        }
    }
}

// ---------------------------------------------------------------------------
// PV: out_pre[b, n, h*128+c] = sum_d attn[bh][c][d] * y[b, n, h*128+d]
// y is fp32; converted to bf16 fragments in registers.
// ---------------------------------------------------------------------------
__global__ __launch_bounds__(256) void pv_kernel(const bf16* __restrict__ attn,
                                                 const float* __restrict__ y,
                                                 bf16* __restrict__ out_pre) {
    constexpr int LDA = HD + 8;                 // 136
    __shared__ bf16 Pw[HD * LDA];               // attn [c][d], padded

    const int bh = blockIdx.y, b = bh / Hn, h = bh % Hn;
    const int nbase = blockIdx.x * 512;
    const int tid = threadIdx.x, wave = tid >> 6, lane = tid & 63;
    const int lm = lane & 15, quad = lane >> 4;

    const bf16* ap = attn + (size_t)bh * HD * HD;
#pragma unroll
    for (int r = 0; r < 8; r++) {
        const int chunk = tid + 256 * r;        // 0..2047
        const int c = chunk >> 4, d0 = (chunk & 15) * 8;
        *reinterpret_cast<int4*>(&Pw[c * LDA + d0]) =
            *reinterpret_cast<const int4*>(ap + (size_t)c * HD + d0);
    }
    __syncthreads();

    const float* yh = y + (size_t)b * Ntok * Cdim + h * HD;
    for (int mt = 0; mt < 8; mt++) {
        const int nrow0 = nbase + wave * 128 + mt * 16;
        f32x4 acc[8] = {};
#pragma unroll
        for (int ks = 0; ks < 4; ks++) {
            const int4 ai = cvt8_f32_to_bf16(yh + (size_t)(nrow0 + lm) * Cdim + ks * 32 + quad * 8);
            const bf16x8 afr = *reinterpret_cast<const bf16x8*>(&ai);
#pragma unroll
            for (int ct = 0; ct < 8; ct++) {
                const bf16x8 bfr = *reinterpret_cast<const bf16x8*>(&Pw[(ct * 16 + lm) * LDA + ks * 32 + quad * 8]);
                acc[ct] = __builtin_amdgcn_mfma_f32_16x16x32_bf16(afr, bfr, acc[ct], 0, 0, 0);
            }
        }
        bf16* op = out_pre + (size_t)(b * Ntok + nrow0) * Cdim + h * HD;
#pragma unroll
        for (int ct = 0; ct < 8; ct++) {
            const int ccol = ct * 16 + lm;
#pragma unroll
            for (int r = 0; r < 4; r++)
                op[(size_t)(quad * 4 + r) * Cdim + ccol] = __float2bfloat16(acc[ct][r]);
        }
    }
}

// ---------------------------------------------------------------------------
extern "C" void kernel_launch(void* const* d_in, const int* in_sizes, int n_in,
                              void* d_out, int out_size, void* d_ws, size_t ws_size,
                              hipStream_t stream) {
    const float* x     = (const float*)d_in[0];
    const float* y     = (const float*)d_in[1];
    const float* Wqkv  = (const float*)d_in[2];
    const float* temp  = (const float*)d_in[3];
    const float* Wproj = (const float*)d_in[4];
    const float* bproj = (const float*)d_in[5];
    float* out = (float*)d_out;

    char* ws = (char*)d_ws;
    size_t o = 0;
    bf16* qkv     = (bf16*)(ws + o); o += (size_t)32768 * 1536 * 2;   // 100.7 MB
    bf16* out_pre = (bf16*)(ws + o); o += (size_t)32768 * 768 * 2;    //  50.3 MB
    bf16* Wt_qkv  = (bf16*)(ws + o); o += (size_t)1536 * 768 * 2;
    bf16* Wt_proj = (bf16*)(ws + o); o += (size_t)768 * 768 * 2;
    float* invn   = (float*)(ws + o); o += (size_t)8 * 1536 * 4;
    bf16* attnw   = (bf16*)(ws + o); o += (size_t)48 * 128 * 128 * 2;

    dim3 tb(32, 8);
    transpose_kernel<<<dim3(1536 / 32, 768 / 32), tb, 0, stream>>>(Wqkv, Wt_qkv, 768, 1536);
    transpose_kernel<<<dim3(768 / 32, 768 / 32), tb, 0, stream>>>(Wproj, Wt_proj, 768, 768);

    // qkv = x @ W_qkv   [32768 x 1536, K=768], fp32 A -> bf16 out
    gemm_bt<true, false, false><<<dim3(1536 / 128, 32768 / 128), 256, 0, stream>>>(
        x, Wt_qkv, nullptr, qkv, 32768, 1536, 768);

    colnorm_kernel<<<dim3(24, 8), 512, 0, stream>>>(qkv, invn);

    gram_softmax_kernel<<<48, 256, 0, stream>>>(qkv, invn, temp, attnw);

    pv_kernel<<<dim3(8, 48), 256, 0, stream>>>(attnw, y, out_pre);

    // out = out_pre @ W_proj + b_proj   [32768 x 768, K=768], bf16 A -> fp32 out
    gemm_bt<false, true, true><<<dim3(768 / 128, 32768 / 128), 256, 0, stream>>>(
        out_pre, Wt_proj, bproj, out, 32768, 768, 768);
}

// Round 3
// 526.859 us; speedup vs baseline: 1.1862x; 1.1862x over previous
//
#include <hip/hip_runtime.h>
#include <hip/hip_bf16.h>

using bf16 = __hip_bfloat16;
typedef __attribute__((ext_vector_type(4))) float f32x4;
typedef __attribute__((ext_vector_type(8))) short bf16x8;   // 8 bf16 = 4 VGPRs (MFMA A/B frag)

constexpr int Ntok   = 4096;
constexpr int Cdim   = 768;
constexpr int Hn     = 6;
constexpr int HD     = 128;
constexpr int QKcols = 1536;   // 2*Cdim

#define AS1 __attribute__((address_space(1)))
#define AS3 __attribute__((address_space(3)))

__device__ inline void gload_lds16(const bf16* g, bf16* l) {
    __builtin_amdgcn_global_load_lds((const AS1 void*)g, (AS3 void*)l, 16, 0, 0);
}

__device__ inline int4 cvt8_f32_to_bf16(const float* p) {
    const float4 a0 = *reinterpret_cast<const float4*>(p);
    const float4 a1 = *reinterpret_cast<const float4*>(p + 4);
    union { int4 i; bf16 h[8]; } u;
    u.h[0] = __float2bfloat16(a0.x); u.h[1] = __float2bfloat16(a0.y);
    u.h[2] = __float2bfloat16(a0.z); u.h[3] = __float2bfloat16(a0.w);
    u.h[4] = __float2bfloat16(a1.x); u.h[5] = __float2bfloat16(a1.y);
    u.h[6] = __float2bfloat16(a1.z); u.h[7] = __float2bfloat16(a1.w);
    return u.i;
}

// ---------------------------------------------------------------------------
// fp32 -> bf16 bulk convert (x). 8 elems/thread.
// ---------------------------------------------------------------------------
__global__ __launch_bounds__(256) void cvt_kernel(const float* __restrict__ in,
                                                  bf16* __restrict__ out) {
    const size_t i = ((size_t)blockIdx.x * 256 + threadIdx.x) * 8;
    *reinterpret_cast<int4*>(out + i) = cvt8_f32_to_bf16(in + i);
}

// ---------------------------------------------------------------------------
// Transpose + cast: W[K][N] fp32 -> Wt[N][K] bf16
// ---------------------------------------------------------------------------
__global__ void transpose_kernel(const float* __restrict__ W, bf16* __restrict__ Wt,
                                 int K, int N) {
    __shared__ bf16 tile[32][33];
    const int n0 = blockIdx.x * 32, k0 = blockIdx.y * 32;
    const int tx = threadIdx.x, ty = threadIdx.y;      // blockDim (32,8)
    for (int i = 0; i < 32; i += 8)
        tile[ty + i][tx] = __float2bfloat16(W[(size_t)(k0 + ty + i) * N + n0 + tx]);
    __syncthreads();
    for (int i = 0; i < 32; i += 8)
        Wt[(size_t)(n0 + ty + i) * K + k0 + tx] = tile[tx][ty + i];
}

// ---------------------------------------------------------------------------
// GEMM: C[M][N] = A[M][K] @ Bt[N][K]^T (+bias). bf16 in, fp32 accum.
// m97 structure: 128x128 tile, BK=32, global_load_lds(16B) staging, unpadded LDS.
// ---------------------------------------------------------------------------
template <bool C_F32, bool BIAS>
__global__ __launch_bounds__(256) void gemm_bt(const bf16* __restrict__ A,
                                               const bf16* __restrict__ Bt,
                                               const float* __restrict__ bias,
                                               void* __restrict__ Cv,
                                               int M, int N, int K) {
    __shared__ bf16 As[128 * 32];
    __shared__ bf16 Bs[128 * 32];

    const int m0   = blockIdx.y * 128, n0 = blockIdx.x * 128;
    const int tid  = threadIdx.x;
    const int wave = tid >> 6, lane = tid & 63;
    const int wq   = wave >> 1, wr = wave & 1;
    const int lm   = lane & 15, quad = lane >> 4;

    // staging map: thread -> (row = tid/4, col = (tid&3)*8); LDS offset == tid*16B
    const int srow = tid >> 2, scol = (tid & 3) * 8;
    const bf16* Ag = A  + (size_t)(m0 + srow) * K + scol;
    const bf16* Bg = Bt + (size_t)(n0 + srow) * K + scol;
    bf16* Al0 = &As[srow * 32 + scol];
    bf16* Al1 = &As[(64 + srow) * 32 + scol];
    bf16* Bl0 = &Bs[srow * 32 + scol];
    bf16* Bl1 = &Bs[(64 + srow) * 32 + scol];

    f32x4 acc[4][4] = {};

    for (int k0 = 0; k0 < K; k0 += 32) {
        __syncthreads();
        gload_lds16(Ag + k0,                Al0);
        gload_lds16(Ag + (size_t)64 * K + k0, Al1);
        gload_lds16(Bg + k0,                Bl0);
        gload_lds16(Bg + (size_t)64 * K + k0, Bl1);
        __syncthreads();

        bf16x8 af[4], bfr[4];
#pragma unroll
        for (int t = 0; t < 4; t++) {
            af[t]  = *reinterpret_cast<const bf16x8*>(&As[(wq * 64 + t * 16 + lm) * 32 + quad * 8]);
            bfr[t] = *reinterpret_cast<const bf16x8*>(&Bs[(wr * 64 + t * 16 + lm) * 32 + quad * 8]);
        }
#pragma unroll
        for (int mt = 0; mt < 4; mt++)
#pragma unroll
            for (int nt = 0; nt < 4; nt++)
                acc[mt][nt] = __builtin_amdgcn_mfma_f32_16x16x32_bf16(af[mt], bfr[nt], acc[mt][nt], 0, 0, 0);
    }

    const int cm = m0 + wq * 64, cn = n0 + wr * 64;
#pragma unroll
    for (int mt = 0; mt < 4; mt++) {
#pragma unroll
        for (int nt = 0; nt < 4; nt++) {
            const int col = cn + nt * 16 + lm;
            const float bv = BIAS ? bias[col] : 0.0f;
#pragma unroll
            for (int r = 0; r < 4; r++) {
                const int row = cm + mt * 16 + quad * 4 + r;
                if constexpr (C_F32)
                    ((float*)Cv)[(size_t)row * N + col] = acc[mt][nt][r] + bv;
                else
                    ((bf16*)Cv)[(size_t)row * N + col] = __float2bfloat16(acc[mt][nt][r] + bv);
            }
        }
    }
}

// ---------------------------------------------------------------------------
// Column sum-of-squares over tokens: invn[b][j] = 1/max(||qkv[b,:,j]||, eps)
// grid (24, 8), block 256; thread: 8 cols (int4), 128 rows
// ---------------------------------------------------------------------------
__global__ __launch_bounds__(256) void colnorm_kernel(const bf16* __restrict__ qkv,
                                                      float* __restrict__ invn) {
    const int b = blockIdx.y, j0 = blockIdx.x * 64;
    const int cg = threadIdx.x & 7;     // col group (8 cols)
    const int rg = threadIdx.x >> 3;    // 32 row groups of 128 rows
    const bf16* p = qkv + (size_t)b * Ntok * QKcols + (size_t)rg * 128 * QKcols + j0 + cg * 8;
    float s[8] = {};
    for (int r = 0; r < 128; r++) {
        bf16 h[8];
        *reinterpret_cast<int4*>(h) = *reinterpret_cast<const int4*>(p + (size_t)r * QKcols);
#pragma unroll
        for (int t = 0; t < 8; t++) { const float v = (float)h[t]; s[t] += v * v; }
    }
    __shared__ float red[256][8];
#pragma unroll
    for (int t = 0; t < 8; t++) red[threadIdx.x][t] = s[t];
    __syncthreads();
    if (threadIdx.x < 64) {
        const int cg2 = threadIdx.x >> 3, t2 = threadIdx.x & 7;
        float tot = 0.0f;
#pragma unroll
        for (int g = 0; g < 32; g++) tot += red[g * 8 + cg2][t2];
        invn[b * QKcols + j0 + threadIdx.x] = 1.0f / fmaxf(sqrtf(tot), 1e-12f);
    }
}

// ---------------------------------------------------------------------------
// Partial Gram: block (bh, nc) computes 128x128 Gram over 512 tokens -> fp32
// ---------------------------------------------------------------------------
__global__ __launch_bounds__(256) void gram_partial_kernel(const bf16* __restrict__ qkv,
                                                           float* __restrict__ partial) {
    constexpr int BKn = 64;
    constexpr int LDT = BKn + 8;                // 72: 2-way aliasing only (free)
    __shared__ bf16 Qt[HD * LDT];
    __shared__ bf16 Kt[HD * LDT];

    const int bh = blockIdx.x, nc = blockIdx.y, b = bh / Hn, h = bh % Hn;
    const int tid = threadIdx.x, wave = tid >> 6, lane = tid & 63;
    const int lm = lane & 15, quad = lane >> 4;
    const size_t base = (size_t)b * Ntok * QKcols;
    const int qoff = h * HD, koff = Cdim + h * HD;

    f32x4 acc[2][8] = {};

    for (int i = 0; i < 8; i++) {
        const int n0 = nc * 512 + i * BKn;
        __syncthreads();
#pragma unroll
        for (int r = 0; r < 4; r++) {
            const int chunk = tid + 256 * r;     // 0..1023
            const int nl = chunk & 63;
            const int j0 = (chunk >> 6) * 8;     // 0..120
            bf16 vq[8], vk[8];
            *reinterpret_cast<int4*>(vq) = *reinterpret_cast<const int4*>(qkv + base + (size_t)(n0 + nl) * QKcols + qoff + j0);
            *reinterpret_cast<int4*>(vk) = *reinterpret_cast<const int4*>(qkv + base + (size_t)(n0 + nl) * QKcols + koff + j0);
#pragma unroll
            for (int t = 0; t < 8; t++) {
                Qt[(j0 + t) * LDT + nl] = vq[t];
                Kt[(j0 + t) * LDT + nl] = vk[t];
            }
        }
        __syncthreads();
#pragma unroll
        for (int ks = 0; ks < 2; ks++) {
            bf16x8 aq[2], bk[8];
#pragma unroll
            for (int mt = 0; mt < 2; mt++)
                aq[mt] = *reinterpret_cast<const bf16x8*>(&Qt[(wave * 32 + mt * 16 + lm) * LDT + ks * 32 + quad * 8]);
#pragma unroll
            for (int dt = 0; dt < 8; dt++)
                bk[dt] = *reinterpret_cast<const bf16x8*>(&Kt[(dt * 16 + lm) * LDT + ks * 32 + quad * 8]);
#pragma unroll
            for (int mt = 0; mt < 2; mt++)
#pragma unroll
                for (int dt = 0; dt < 8; dt++)
                    acc[mt][dt] = __builtin_amdgcn_mfma_f32_16x16x32_bf16(aq[mt], bk[dt], acc[mt][dt], 0, 0, 0);
        }
    }

    float* pp = partial + ((size_t)(bh * 8 + nc) * HD) * HD;
#pragma unroll
    for (int mt = 0; mt < 2; mt++)
#pragma unroll
        for (int dt = 0; dt < 8; dt++)
#pragma unroll
            for (int r = 0; r < 4; r++) {
                const int c = wave * 32 + mt * 16 + quad * 4 + r;
                pp[(size_t)c * HD + dt * 16 + lm] = acc[mt][dt][r];
            }
}

// ---------------------------------------------------------------------------
// Reduce partials + scale + softmax -> attn bf16. grid 48, block 256.
// thread: row = tid/2, half = tid&1 (64 cols)
// ---------------------------------------------------------------------------
__global__ __launch_bounds__(256) void gram_reduce_softmax(const float* __restrict__ partial,
                                                           const float* __restrict__ invn,
                                                           const float* __restrict__ temp,
                                                           bf16* __restrict__ attn) {
    const int bh = blockIdx.x, b = bh / Hn, h = bh % Hn;
    const int r = threadIdx.x >> 1, hf = threadIdx.x & 1;
    const float th = temp[h];
    const float* invq = invn + b * QKcols + h * HD;
    const float* invk = invn + b * QKcols + Cdim + h * HD;

    float v[64];
    const float* pbase = partial + ((size_t)bh * 8 * HD + r) * HD + hf * 64;
#pragma unroll
    for (int t = 0; t < 64; t += 4)
        *reinterpret_cast<float4*>(&v[t]) = *reinterpret_cast<const float4*>(&pbase[t]);
    for (int p = 1; p < 8; p++) {
        const float* pp = pbase + (size_t)p * HD * HD;
#pragma unroll
        for (int t = 0; t < 64; t += 4) {
            const float4 u = *reinterpret_cast<const float4*>(&pp[t]);
            v[t] += u.x; v[t + 1] += u.y; v[t + 2] += u.z; v[t + 3] += u.w;
        }
    }
    const float iq = invq[r] * th;
    float mx = -1e30f;
#pragma unroll
    for (int t = 0; t < 64; t++) { v[t] *= iq * invk[hf * 64 + t]; mx = fmaxf(mx, v[t]); }
    mx = fmaxf(mx, __shfl_xor(mx, 1, 64));
    float sum = 0.0f;
#pragma unroll
    for (int t = 0; t < 64; t++) { v[t] = __expf(v[t] - mx); sum += v[t]; }
    sum += __shfl_xor(sum, 1, 64);
    const float inv = 1.0f / sum;
    bf16* orow = attn + ((size_t)bh * HD + r) * HD + hf * 64;
#pragma unroll
    for (int t = 0; t < 64; t++) orow[t] = __float2bfloat16(v[t] * inv);
}

// ---------------------------------------------------------------------------
// PV: out_pre[b, n, h*128+c] = sum_d attn[bh][c][d] * y[b, n, h*128+d]
// ---------------------------------------------------------------------------
__global__ __launch_bounds__(256) void pv_kernel(const bf16* __restrict__ attn,
                                                 const float* __restrict__ y,
                                                 bf16* __restrict__ out_pre) {
    constexpr int LDA = HD + 8;                 // 136
    __shared__ bf16 Pw[HD * LDA];

    const int bh = blockIdx.y, b = bh / Hn, h = bh % Hn;
    const int nbase = blockIdx.x * 512;
    const int tid = threadIdx.x, wave = tid >> 6, lane = tid & 63;
    const int lm = lane & 15, quad = lane >> 4;

    const bf16* ap = attn + (size_t)bh * HD * HD;
#pragma unroll
    for (int r = 0; r < 8; r++) {
        const int chunk = tid + 256 * r;        // 0..2047
        const int c = chunk >> 4, d0 = (chunk & 15) * 8;
        *reinterpret_cast<int4*>(&Pw[c * LDA + d0]) =
            *reinterpret_cast<const int4*>(ap + (size_t)c * HD + d0);
    }
    __syncthreads();

    const float* yh = y + (size_t)b * Ntok * Cdim + h * HD;
    for (int mt = 0; mt < 8; mt++) {
        const int nrow0 = nbase + wave * 128 + mt * 16;
        f32x4 acc[8] = {};
#pragma unroll
        for (int ks = 0; ks < 4; ks++) {
            const int4 ai = cvt8_f32_to_bf16(yh + (size_t)(nrow0 + lm) * Cdim + ks * 32 + quad * 8);
            const bf16x8 afr = *reinterpret_cast<const bf16x8*>(&ai);
#pragma unroll
            for (int ct = 0; ct < 8; ct++) {
                const bf16x8 bfr = *reinterpret_cast<const bf16x8*>(&Pw[(ct * 16 + lm) * LDA + ks * 32 + quad * 8]);
                acc[ct] = __builtin_amdgcn_mfma_f32_16x16x32_bf16(afr, bfr, acc[ct], 0, 0, 0);
            }
        }
        bf16* op = out_pre + (size_t)(b * Ntok + nrow0) * Cdim + h * HD;
#pragma unroll
        for (int ct = 0; ct < 8; ct++) {
            const int ccol = ct * 16 + lm;
#pragma unroll
            for (int r = 0; r < 4; r++)
                op[(size_t)(quad * 4 + r) * Cdim + ccol] = __float2bfloat16(acc[ct][r]);
        }
    }
}

// ---------------------------------------------------------------------------
extern "C" void kernel_launch(void* const* d_in, const int* in_sizes, int n_in,
                              void* d_out, int out_size, void* d_ws, size_t ws_size,
                              hipStream_t stream) {
    const float* x     = (const float*)d_in[0];
    const float* y     = (const float*)d_in[1];
    const float* Wqkv  = (const float*)d_in[2];
    const float* temp  = (const float*)d_in[3];
    const float* Wproj = (const float*)d_in[4];
    const float* bproj = (const float*)d_in[5];
    float* out = (float*)d_out;

    char* ws = (char*)d_ws;
    size_t o = 0;
    bf16* qkv     = (bf16*)(ws + o); o += (size_t)32768 * 1536 * 2;       // 100.7 MB
    bf16* xb      = (bf16*)(ws + o);                                      //  50.3 MB slab...
    float* partial = (float*)xb;      o += (size_t)48 * 8 * 128 * 128 * 4; // ...reused as partial (25.2 MB) after GEMM1
    o = (o < (size_t)32768 * 1536 * 2 + (size_t)32768 * 768 * 2)
            ? (size_t)32768 * 1536 * 2 + (size_t)32768 * 768 * 2 : o;
    bf16* out_pre = (bf16*)(ws + o); o += (size_t)32768 * 768 * 2;        //  50.3 MB
    bf16* Wt_qkv  = (bf16*)(ws + o); o += (size_t)1536 * 768 * 2;
    bf16* Wt_proj = (bf16*)(ws + o); o += (size_t)768 * 768 * 2;
    float* invn   = (float*)(ws + o); o += (size_t)8 * 1536 * 4;
    bf16* attnw   = (bf16*)(ws + o); o += (size_t)48 * 128 * 128 * 2;

    dim3 tb(32, 8);
    transpose_kernel<<<dim3(1536 / 32, 768 / 32), tb, 0, stream>>>(Wqkv, Wt_qkv, 768, 1536);
    transpose_kernel<<<dim3(768 / 32, 768 / 32), tb, 0, stream>>>(Wproj, Wt_proj, 768, 768);

    // x fp32 -> bf16 (25.2M elems / 8 per thread / 256 per block)
    cvt_kernel<<<12288, 256, 0, stream>>>(x, xb);

    // qkv = xb @ W_qkv   [32768 x 1536, K=768]
    gemm_bt<false, false><<<dim3(1536 / 128, 32768 / 128), 256, 0, stream>>>(
        xb, Wt_qkv, nullptr, qkv, 32768, 1536, 768);

    colnorm_kernel<<<dim3(24, 8), 256, 0, stream>>>(qkv, invn);

    // partial aliases xb (xb dead after GEMM1)
    gram_partial_kernel<<<dim3(48, 8), 256, 0, stream>>>(qkv, partial);
    gram_reduce_softmax<<<48, 256, 0, stream>>>(partial, invn, temp, attnw);

    pv_kernel<<<dim3(8, 48), 256, 0, stream>>>(attnw, y, out_pre);

    // out = out_pre @ W_proj + b_proj   [32768 x 768, K=768]
    gemm_bt<true, true><<<dim3(768 / 128, 32768 / 128), 256, 0, stream>>>(
        out_pre, Wt_proj, bproj, out, 32768, 768, 768);
}